// Round 19
// baseline (160.258 us; speedup 1.0000x reference)
//
#include <hip/hip_runtime.h>
#include <stdint.h>

// Fused MLP decode, MFMA f16. ROUND 19: R18 base (kernel-best 92.6-94.4us)
// + one-time emb f32->f16 conversion (emb_cvt pre-kernel into d_ws).
// The loop spent 8 cvt_pkrtz + 32B of f32 loads per tile re-converting
// emb rows drawn from a 511x32 table. Convert ONCE (same cvt_pkrtz
// rounding -> bit-identical fragments to R18); the main loop loads the
// X0 fragment as one aligned 16B half8. Deletes 8 pkh/tile, halves emb
// bytes, shrinks pipeline carried-state shuffling. Multi-launch on the
// stream is graph-capture-safe (R6 ran 5 dispatches).
// Port model (R18): ~672 of 915 cyc/wave-tile used (~73%) -- remaining
// stall is dep-chain at 2 pinned waves/SIMD; this cuts the 672.
// Kept (validated): zero-LDS loop + modulo-2 interleave (R12), weights
// AGPR-resident (R4/R8), hmap-permuted W1 (R11), b1 as true MFMA C (R18),
// staged-Wout dot-MFMA epilogue (R16), usilu1 (R15), split Chebyshev
// (R17), grid 512 = 2 blocks/CU (R17), tix/rho 2-ahead + emb 1-ahead
// prefetch (R13 lesson), lb(256,3). Loop: zero DS ops, zero barriers.

typedef _Float16 half8  __attribute__((ext_vector_type(8)));
typedef _Float16 half4v __attribute__((ext_vector_type(4)));
typedef _Float16 half2v __attribute__((ext_vector_type(2)));
typedef float f32x4 __attribute__((ext_vector_type(4)));

#define LOG2E 1.44269504088896340736f
#define NLN2  -0.6931471805599453f         // -ln2 = 1/(-log2e)
#define CSCL  -1.44269504088896340736f     // c = -log2e
#define BASE_LOGIT -0.84729786038720367f   // log(0.3/0.7)
#define CSANMAX 28700.0f
#define IC_VAL 8610.0f                     // 0.3 * 28700

__device__ __forceinline__ float fast_exp2(float x) { return __builtin_amdgcn_exp2f(x); }
__device__ __forceinline__ float fast_rcp(float x)  { return __builtin_amdgcn_rcpf(x); }
// direct u-domain silu: input u (= c*x), output p = u*sigma = c*silu(x).
__device__ __forceinline__ float usilu1(float u) {
  return u * fast_rcp(1.0f + fast_exp2(u));
}
__device__ __forceinline__ half2v pkh(float a, float b) {
  return __builtin_bit_cast(half2v, __builtin_amdgcn_cvt_pkrtz(a, b));
}

union H8 { half8 v8; half2v v2[4]; half4v v4[2]; };
union H4 { half4v v4; half2v v2[2]; };

// ---- pre-kernel: emb (511x32 f32) -> f16 once, cvt_pkrtz rounding ----
__global__ __launch_bounds__(256) void emb_cvt(
    const float* __restrict__ emb, _Float16* __restrict__ embh, int nelem2)
{
  const int i = blockIdx.x * 256 + threadIdx.x;   // one f16 PAIR per thread
  if (i < nelem2) {
    const float a = emb[i * 2];
    const float b = emb[i * 2 + 1];
    *(half2v*)&embh[i * 2] = pkh(a, b);           // same rounding as R18
  }
}

__global__ __launch_bounds__(256, 3) void mlp_kernel(
    const int* __restrict__ tix, const float* __restrict__ rho,
    const _Float16* __restrict__ embh, const float* __restrict__ W0,
    const float* __restrict__ b0, const float* __restrict__ W1,
    const float* __restrict__ b1, const float* __restrict__ Wout,
    const float* __restrict__ bout, float* __restrict__ out, int ntiles)
{
  // Weight staging ONLY (init, 16384 B). No H buffer.
  __shared__ __align__(16) _Float16 stage[2][2][4][64][8];

  const int tid  = threadIdx.x;
  const int wid  = tid >> 6;
  const int lane = tid & 63;
  const int m    = lane & 15;
  const int q    = lane >> 4;

  // ---- init: wave 0 builds the swizzled weight fragments ----
  // W0 (A-op, => W0^T): k=s*32+q*8+j, n=t*16+m; feature rows PERMUTED
  // (k-window 32..63 = [cos1..8|sin1..8|rho,b0(1.0),0pad]); pre-scaled by c.
  // W1 (A-op, => W1^T): rows hmap-permuted so L1's B-operand is L0's
  // register output directly: hmap(k) = (s*2+(j>>2))*16 + q*4 + (j&3).
  if (wid == 0) {
#pragma unroll
    for (int t = 0; t < 4; ++t) {
#pragma unroll
      for (int s = 0; s < 2; ++s) {
        half8 f0, f1;
#pragma unroll
        for (int j = 0; j < 8; ++j) {
          const int k = s * 32 + q * 8 + j;
          const int n = t * 16 + m;
          float v0;
          if (k < 32) {
            v0 = W0[k * 64 + n];
          } else {
            const int kn = k - 32;
            v0 = (kn < 16) ? W0[(33 + kn) * 64 + n]
               : (kn == 16) ? W0[32 * 64 + n]
               : (kn == 17) ? b0[n] : 0.0f;
          }
          f0[j] = (_Float16)(CSCL * v0);
          const int hm = (s * 2 + (j >> 2)) * 16 + q * 4 + (j & 3);
          f1[j] = (_Float16)W1[hm * 64 + n];   // W1 UNSCALED, hmap-permuted
        }
        *(half8*)&stage[0][s][t][lane][0] = f0;
        *(half8*)&stage[1][s][t][lane][0] = f1;
      }
    }
  }

  // ---- persistent epilogue constants ----
  // b1 as TRUE L1 C-operand (u-domain): lane (q,m) owns h = t*16 + q*4 + r.
  f32x4 bq1acc[4];
#pragma unroll
  for (int t = 0; t < 4; ++t) {
    const f32x4 bv = *(const f32x4*)(b1 + t * 16 + q * 4);
#pragma unroll
    for (int r = 0; r < 4; ++r) bq1acc[t][r] = CSCL * bv[r];
  }
  // Wout as dot-MFMA A-fragments (rows identical; -ln2-scaled):
  // A[row=*][k=q*8+j] = NLN2 * Wout[h'], h' = (j>>2)*16+q*4+(j&3) (+32 B-half).
  H8 wdA, wdB;
#pragma unroll
  for (int a = 0; a < 4; ++a) {
    const int j0 = 2 * a, j1 = 2 * a + 1;
    const int h0 = ((j0 >> 2) * 16) + q * 4 + (j0 & 3);
    const int h1 = ((j1 >> 2) * 16) + q * 4 + (j1 & 3);
    wdA.v2[a] = pkh(NLN2 * Wout[h0],      NLN2 * Wout[h1]);
    wdB.v2[a] = pkh(NLN2 * Wout[32 + h0], NLN2 * Wout[32 + h1]);
  }
  const float boutBL = bout[0] + BASE_LOGIT;
  const f32x4 cBL = {boutBL, boutBL, boutBL, boutBL};   // dot-MFMA C-operand

  __syncthreads();   // staged weights visible

  // ---- hoist ALL weight fragments to registers (loop-invariant) ----
  half8 w0A[4], w0B[4], w1A[4], w1B[4];
#pragma unroll
  for (int t = 0; t < 4; ++t) {
    w0A[t] = *(const half8*)&stage[0][0][t][lane][0];
    w0B[t] = *(const half8*)&stage[0][1][t][lane][0];
    w1A[t] = *(const half8*)&stage[1][0][t][lane][0];
    w1B[t] = *(const half8*)&stage[1][1][t][lane][0];
  }

  const f32x4 z = {0.0f, 0.0f, 0.0f, 0.0f};
  const int S = gridDim.x * 4;

  int tg = blockIdx.x * 4 + wid;
  if (tg >= ntiles) return;          // after the barrier: safe
  const int lim = ntiles - 1;

  // ---- phase1: feat -> L0 -> silu -> packed Y (registers only) ----
  auto phase1 = [&](float rhp, half8 X0v, H8& Y0o, H8& Y1o) {
    const float rev = 0.5f * rhp;  // v_sin/v_cos take revolutions
    const float c1  = __builtin_amdgcn_cosf(rev);
    const float s1f = __builtin_amdgcn_sinf(rev);
    const float tc  = 2.0f * c1;
    const float x1v = (q == 0) ? c1 : ((q == 1) ? s1f : 0.0f);
    const float x0v = (q == 0) ? 1.0f : 0.0f;
    // even/odd split: x_{k+2} = uu*x_k - x_{k-2}, uu = 2cos(2a) = tc^2-2.
    const float x2v = tc * x1v - x0v;
    const float x3v = tc * x2v - x1v;
    const float uu  = tc * tc - 2.0f;
    const float x4v = uu * x2v - x0v;
    const float x5v = uu * x3v - x1v;
    const float x6v = uu * x4v - x2v;
    const float x7v = uu * x5v - x3v;
    const float x8v = uu * x6v - x4v;
    H8 X1;
    X1.v2[0] = (q == 2) ? pkh(rhp, 1.0f) : pkh(x1v, x2v);  // q==2: (rho, b0-slot)
    X1.v2[1] = pkh(x3v, x4v);
    X1.v2[2] = pkh(x5v, x6v);
    X1.v2[3] = pkh(x7v, x8v);

    f32x4 acc[4];
#pragma unroll
    for (int t = 0; t < 4; ++t) {
      f32x4 a = __builtin_amdgcn_mfma_f32_16x16x32_f16(w0A[t], X0v, z, 0, 0, 0);
      a = __builtin_amdgcn_mfma_f32_16x16x32_f16(w0B[t], X1.v8, a, 0, 0, 0);
      acc[t] = a;
    }
    H4 hh[4];
#pragma unroll
    for (int t = 0; t < 4; ++t) {
      const float p0 = usilu1(acc[t][0]);
      const float p1 = usilu1(acc[t][1]);
      const float p2 = usilu1(acc[t][2]);
      const float p3 = usilu1(acc[t][3]);
      hh[t].v2[0] = pkh(p0, p1);
      hh[t].v2[1] = pkh(p2, p3);
    }
    Y0o.v4[0] = hh[0].v4; Y0o.v4[1] = hh[1].v4;   // hmap makes this exact
    Y1o.v4[0] = hh[2].v4; Y1o.v4[1] = hh[3].v4;
  };

  // ---- phase2: L1(carried Y, C=c*b1) -> silu -> pack -> dot-MFMA -> store ----
  auto phase2 = [&](const H8& Y0p, const H8& Y1p, int icP, int tgP) {
    f32x4 acc[4];
#pragma unroll
    for (int t = 0; t < 4; ++t) {
      f32x4 a = __builtin_amdgcn_mfma_f32_16x16x32_f16(w1A[t], Y0p.v8, bq1acc[t], 0, 0, 0);
      a = __builtin_amdgcn_mfma_f32_16x16x32_f16(w1B[t], Y1p.v8, a, 0, 0, 0);
      acc[t] = a;   // u = W1^T p + c*b1 directly (bias folded into MFMA C)
    }
    H4 hh2[4];
#pragma unroll
    for (int t = 0; t < 4; ++t) {
      hh2[t].v2[0] = pkh(usilu1(acc[t][0]), usilu1(acc[t][1]));
      hh2[t].v2[1] = pkh(usilu1(acc[t][2]), usilu1(acc[t][3]));
    }
    H8 B0, B1;
    B0.v4[0] = hh2[0].v4; B0.v4[1] = hh2[1].v4;   // B[k][col=m], h'(k) staged
    B1.v4[0] = hh2[2].v4; B1.v4[1] = hh2[3].v4;
    f32x4 d2 = __builtin_amdgcn_mfma_f32_16x16x32_f16(wdA.v8, B0.v8, cBL, 0, 0, 0);
    d2 = __builtin_amdgcn_mfma_f32_16x16x32_f16(wdB.v8, B1.v8, d2, 0, 0, 0);
    // all A rows equal -> every lane's d2[0] = dot(point m) + boutBL
    const float theta = fast_rcp(1.0f + fast_exp2(-LOG2E * d2[0]));
    const float val = (icP == 0) ? IC_VAL : theta * CSANMAX;
    if (q == 0) out[tgP * 16 + m] = val;
  };

  // ---- prologue: run phase1 on tile tg; prep inputs for tile tg+S ----
  int   tC = tix[tg * 16 + m];
  float rC = rho[tg * 16 + m];
  const int tg1 = min(tg + S, lim);
  int   tN = tix[tg1 * 16 + m];
  float rN = rho[tg1 * 16 + m];
  H8 X0C;
  {
    const int idx = min(max(tC - 1, 0), 510);
    X0C.v8 = *(const half8*)(embh + (size_t)idx * 32 + q * 8);   // 16B direct
  }
  H8 Y0p, Y1p;
  phase1(rC, X0C.v8, Y0p, Y1p);
  int icP = tC, tgP = tg;
  {
    const int idx = min(max(tN - 1, 0), 510);
    X0C.v8 = *(const half8*)(embh + (size_t)idx * 32 + q * 8);
  }
  tC = tN; rC = rN;
  {
    const int tg2 = min(tg + 2 * S, lim);
    tN = tix[tg2 * 16 + m];
    rN = rho[tg2 * 16 + m];
  }
  tg += S;

  // ---- steady state: phase2(tile k-1, carried Y) ; phase1(tile k) ----
  while (tg < ntiles) {
    // prefetch: tix/rho 2 tiles ahead; emb 1 tile ahead (tN is >=1 iter old)
    const int tg2 = min(tg + 2 * S, lim);
    const int   tQ = tix[tg2 * 16 + m];
    const float rQ = rho[tg2 * 16 + m];
    const int idxN = min(max(tN - 1, 0), 510);
    const half8 X0N = *(const half8*)(embh + (size_t)idxN * 32 + q * 8);

    phase2(Y0p, Y1p, icP, tgP);        // finish previous tile (reg-only deps)
    phase1(rC, X0C.v8, Y0p, Y1p);      // start current tile (independent)

    icP = tC; tgP = tg;
    X0C.v8 = X0N;                      // fragment carried directly, no repack
    tC = tN; rC = rN;
    tN = tQ; rN = rQ;
    tg += S;
  }

  // ---- epilogue: drain the last tile ----
  phase2(Y0p, Y1p, icP, tgP);
}

extern "C" void kernel_launch(void* const* d_in, const int* in_sizes, int n_in,
                              void* d_out, int out_size, void* d_ws, size_t ws_size,
                              hipStream_t stream) {
  const int*   tix  = (const int*)d_in[0];
  const float* rho  = (const float*)d_in[1];
  const float* emb  = (const float*)d_in[2];
  const float* W0   = (const float*)d_in[3];
  const float* b0   = (const float*)d_in[4];
  const float* W1   = (const float*)d_in[5];
  const float* b1   = (const float*)d_in[6];
  const float* Wout = (const float*)d_in[7];
  const float* bout = (const float*)d_in[8];
  float* outp = (float*)d_out;

  const int n      = in_sizes[0];    // 2,000,000 (divisible by 16)
  const int ntiles = n / 16;         // 125,000 tiles of 16 points

  // ---- one-time emb f32->f16 into workspace (32704 B) ----
  _Float16* embh = (_Float16*)d_ws;
  const int nelem2 = (511 * 32) / 2;               // f16 pairs
  emb_cvt<<<dim3((nelem2 + 255) / 256), dim3(256), 0, stream>>>(emb, embh, nelem2);

  // 4-wave blocks, 16384 B LDS. Grid 512 = exactly 2 blocks/CU (measured
  // residency): ~61 iters/wave, prologue/drain amortized 2x vs 1024.
  int grid = 512;
  const int maxg = (ntiles + 3) / 4;
  if (grid > maxg) grid = maxg;
  mlp_kernel<<<dim3(grid), dim3(256), 0, stream>>>(
      tix, rho, embh, W0, b0, W1, b1, Wout, bout, outp, ntiles);
}

// Round 20
// 156.744 us; speedup vs baseline: 1.0224x; 1.0224x over previous
//
#include <hip/hip_runtime.h>
#include <stdint.h>

// Fused MLP decode, MFMA f16. ROUND 20: 2-tile-per-iteration pipeline on
// the LEAN R19 base (kernel-best 91.0-92.6us).
// R9's pair-widening spilled (397MB scratch) -- but its state was fat
// (LDS H pair-buffers, f32 emb prefetch x4, duplicated scaffolding). R19's
// state is lean: emb carried as ONE f16 half8/tile, Y in 8 regs/tile,
// zero-LDS. Doubling the pipeline adds ~35 carried regs from VGPR=72;
// occupancy is proven flat over 72-100+ (R8/R11) -> free if no spill.
// Payoff: 4 independent ~300cy chains per scheduling region (2x phase2 +
// 2x phase1, all different tiles) vs 2 -- attacks the ~28% dep-chain
// stall; addressing amortizes 2x; stores merge to one 128B wave-store.
// PRE-COMMITTED: WRITE_SIZE must stay 7.81MB (jump = spill = revert to
// R19 as final). Expected kernel 80-86us if ILP theory holds.
// Kept (validated): zero-LDS loop + interleave (R12), weights AGPR-
// resident (R4/R8), hmap-permuted W1 (R11), b1 as true MFMA C (R18),
// staged-Wout dot-MFMA epilogue (R16), usilu1 (R15), split Chebyshev
// (R17), grid 512 = 2 blocks/CU (R17), f16 emb table in d_ws (R19),
// tix/rho 2-ahead + emb 1-ahead prefetch (R13 lesson), lb(256,3).
// Loop: zero DS ops, zero barriers. n % 32 == 0 (2,000,000 = 32*62,500).

typedef _Float16 half8  __attribute__((ext_vector_type(8)));
typedef _Float16 half4v __attribute__((ext_vector_type(4)));
typedef _Float16 half2v __attribute__((ext_vector_type(2)));
typedef float f32x4 __attribute__((ext_vector_type(4)));

#define LOG2E 1.44269504088896340736f
#define NLN2  -0.6931471805599453f         // -ln2 = 1/(-log2e)
#define CSCL  -1.44269504088896340736f     // c = -log2e
#define BASE_LOGIT -0.84729786038720367f   // log(0.3/0.7)
#define CSANMAX 28700.0f
#define IC_VAL 8610.0f                     // 0.3 * 28700

__device__ __forceinline__ float fast_exp2(float x) { return __builtin_amdgcn_exp2f(x); }
__device__ __forceinline__ float fast_rcp(float x)  { return __builtin_amdgcn_rcpf(x); }
// direct u-domain silu: input u (= c*x), output p = u*sigma = c*silu(x).
__device__ __forceinline__ float usilu1(float u) {
  return u * fast_rcp(1.0f + fast_exp2(u));
}
__device__ __forceinline__ half2v pkh(float a, float b) {
  return __builtin_bit_cast(half2v, __builtin_amdgcn_cvt_pkrtz(a, b));
}

union H8 { half8 v8; half2v v2[4]; half4v v4[2]; };
union H4 { half4v v4; half2v v2[2]; };

// ---- pre-kernel: emb (511x32 f32) -> f16 once, cvt_pkrtz rounding ----
__global__ __launch_bounds__(256) void emb_cvt(
    const float* __restrict__ emb, _Float16* __restrict__ embh, int nelem2)
{
  const int i = blockIdx.x * 256 + threadIdx.x;   // one f16 PAIR per thread
  if (i < nelem2) {
    const float a = emb[i * 2];
    const float b = emb[i * 2 + 1];
    *(half2v*)&embh[i * 2] = pkh(a, b);           // same rounding as R18
  }
}

__global__ __launch_bounds__(256, 3) void mlp_kernel(
    const int* __restrict__ tix, const float* __restrict__ rho,
    const _Float16* __restrict__ embh, const float* __restrict__ W0,
    const float* __restrict__ b0, const float* __restrict__ W1,
    const float* __restrict__ b1, const float* __restrict__ Wout,
    const float* __restrict__ bout, float* __restrict__ out, int npairs)
{
  // Weight staging ONLY (init, 16384 B). No H buffer.
  __shared__ __align__(16) _Float16 stage[2][2][4][64][8];

  const int tid  = threadIdx.x;
  const int wid  = tid >> 6;
  const int lane = tid & 63;
  const int m    = lane & 15;
  const int q    = lane >> 4;

  // ---- init: wave 0 builds the swizzled weight fragments ----
  // W0 (A-op, => W0^T): k=s*32+q*8+j, n=t*16+m; feature rows PERMUTED
  // (k-window 32..63 = [cos1..8|sin1..8|rho,b0(1.0),0pad]); pre-scaled by c.
  // W1 (A-op, => W1^T): rows hmap-permuted so L1's B-operand is L0's
  // register output directly: hmap(k) = (s*2+(j>>2))*16 + q*4 + (j&3).
  if (wid == 0) {
#pragma unroll
    for (int t = 0; t < 4; ++t) {
#pragma unroll
      for (int s = 0; s < 2; ++s) {
        half8 f0, f1;
#pragma unroll
        for (int j = 0; j < 8; ++j) {
          const int k = s * 32 + q * 8 + j;
          const int n = t * 16 + m;
          float v0;
          if (k < 32) {
            v0 = W0[k * 64 + n];
          } else {
            const int kn = k - 32;
            v0 = (kn < 16) ? W0[(33 + kn) * 64 + n]
               : (kn == 16) ? W0[32 * 64 + n]
               : (kn == 17) ? b0[n] : 0.0f;
          }
          f0[j] = (_Float16)(CSCL * v0);
          const int hm = (s * 2 + (j >> 2)) * 16 + q * 4 + (j & 3);
          f1[j] = (_Float16)W1[hm * 64 + n];   // W1 UNSCALED, hmap-permuted
        }
        *(half8*)&stage[0][s][t][lane][0] = f0;
        *(half8*)&stage[1][s][t][lane][0] = f1;
      }
    }
  }

  // ---- persistent epilogue constants ----
  // b1 as TRUE L1 C-operand (u-domain): lane (q,m) owns h = t*16 + q*4 + r.
  f32x4 bq1acc[4];
#pragma unroll
  for (int t = 0; t < 4; ++t) {
    const f32x4 bv = *(const f32x4*)(b1 + t * 16 + q * 4);
#pragma unroll
    for (int r = 0; r < 4; ++r) bq1acc[t][r] = CSCL * bv[r];
  }
  // Wout as dot-MFMA A-fragments (rows identical; -ln2-scaled):
  // A[row=*][k=q*8+j] = NLN2 * Wout[h'], h' = (j>>2)*16+q*4+(j&3) (+32 B-half).
  H8 wdA, wdB;
#pragma unroll
  for (int a = 0; a < 4; ++a) {
    const int j0 = 2 * a, j1 = 2 * a + 1;
    const int h0 = ((j0 >> 2) * 16) + q * 4 + (j0 & 3);
    const int h1 = ((j1 >> 2) * 16) + q * 4 + (j1 & 3);
    wdA.v2[a] = pkh(NLN2 * Wout[h0],      NLN2 * Wout[h1]);
    wdB.v2[a] = pkh(NLN2 * Wout[32 + h0], NLN2 * Wout[32 + h1]);
  }
  const float boutBL = bout[0] + BASE_LOGIT;
  const f32x4 cBL = {boutBL, boutBL, boutBL, boutBL};   // dot-MFMA C-operand

  __syncthreads();   // staged weights visible

  // ---- hoist ALL weight fragments to registers (loop-invariant) ----
  half8 w0A[4], w0B[4], w1A[4], w1B[4];
#pragma unroll
  for (int t = 0; t < 4; ++t) {
    w0A[t] = *(const half8*)&stage[0][0][t][lane][0];
    w0B[t] = *(const half8*)&stage[0][1][t][lane][0];
    w1A[t] = *(const half8*)&stage[1][0][t][lane][0];
    w1B[t] = *(const half8*)&stage[1][1][t][lane][0];
  }

  const f32x4 z = {0.0f, 0.0f, 0.0f, 0.0f};
  const int W = gridDim.x * 4;

  int p = blockIdx.x * 4 + wid;      // pair index: tiles (2p, 2p+1)
  if (p >= npairs) return;           // after the barrier: safe
  const int plim = npairs - 1;

  // ---- phase1: feat -> L0 -> silu -> packed Y (registers only) ----
  auto phase1 = [&](float rhp, half8 X0v, H8& Y0o, H8& Y1o) {
    const float rev = 0.5f * rhp;  // v_sin/v_cos take revolutions
    const float c1  = __builtin_amdgcn_cosf(rev);
    const float s1f = __builtin_amdgcn_sinf(rev);
    const float tc  = 2.0f * c1;
    const float x1v = (q == 0) ? c1 : ((q == 1) ? s1f : 0.0f);
    const float x0v = (q == 0) ? 1.0f : 0.0f;
    // even/odd split: x_{k+2} = uu*x_k - x_{k-2}, uu = 2cos(2a) = tc^2-2.
    const float x2v = tc * x1v - x0v;
    const float x3v = tc * x2v - x1v;
    const float uu  = tc * tc - 2.0f;
    const float x4v = uu * x2v - x0v;
    const float x5v = uu * x3v - x1v;
    const float x6v = uu * x4v - x2v;
    const float x7v = uu * x5v - x3v;
    const float x8v = uu * x6v - x4v;
    H8 X1;
    X1.v2[0] = (q == 2) ? pkh(rhp, 1.0f) : pkh(x1v, x2v);  // q==2: (rho, b0-slot)
    X1.v2[1] = pkh(x3v, x4v);
    X1.v2[2] = pkh(x5v, x6v);
    X1.v2[3] = pkh(x7v, x8v);

    f32x4 acc[4];
#pragma unroll
    for (int t = 0; t < 4; ++t) {
      f32x4 a = __builtin_amdgcn_mfma_f32_16x16x32_f16(w0A[t], X0v, z, 0, 0, 0);
      a = __builtin_amdgcn_mfma_f32_16x16x32_f16(w0B[t], X1.v8, a, 0, 0, 0);
      acc[t] = a;
    }
    H4 hh[4];
#pragma unroll
    for (int t = 0; t < 4; ++t) {
      hh[t].v2[0] = pkh(usilu1(acc[t][0]), usilu1(acc[t][1]));
      hh[t].v2[1] = pkh(usilu1(acc[t][2]), usilu1(acc[t][3]));
    }
    Y0o.v4[0] = hh[0].v4; Y0o.v4[1] = hh[1].v4;   // hmap makes this exact
    Y1o.v4[0] = hh[2].v4; Y1o.v4[1] = hh[3].v4;
  };

  // ---- phase2core: L1(carried Y, C=c*b1) -> silu -> dot-MFMA -> theta ----
  auto phase2core = [&](const H8& Y0p, const H8& Y1p) -> float {
    f32x4 acc[4];
#pragma unroll
    for (int t = 0; t < 4; ++t) {
      f32x4 a = __builtin_amdgcn_mfma_f32_16x16x32_f16(w1A[t], Y0p.v8, bq1acc[t], 0, 0, 0);
      a = __builtin_amdgcn_mfma_f32_16x16x32_f16(w1B[t], Y1p.v8, a, 0, 0, 0);
      acc[t] = a;   // u = W1^T p + c*b1 (bias folded into MFMA C)
    }
    H4 hh2[4];
#pragma unroll
    for (int t = 0; t < 4; ++t) {
      hh2[t].v2[0] = pkh(usilu1(acc[t][0]), usilu1(acc[t][1]));
      hh2[t].v2[1] = pkh(usilu1(acc[t][2]), usilu1(acc[t][3]));
    }
    H8 B0, B1;
    B0.v4[0] = hh2[0].v4; B0.v4[1] = hh2[1].v4;   // B[k][col=m], h'(k) staged
    B1.v4[0] = hh2[2].v4; B1.v4[1] = hh2[3].v4;
    f32x4 d2 = __builtin_amdgcn_mfma_f32_16x16x32_f16(wdA.v8, B0.v8, cBL, 0, 0, 0);
    d2 = __builtin_amdgcn_mfma_f32_16x16x32_f16(wdB.v8, B1.v8, d2, 0, 0, 0);
    // all A rows equal -> every lane's d2[0] = dot(point m) + boutBL
    return fast_rcp(1.0f + fast_exp2(-LOG2E * d2[0]));
  };

  // ---- pipeline state ----
  int   tCa, tCb, tNa, tNb, icPa, icPb, pP;
  float rCa, rCb, rNa, rNb;
  H8 X0Ca, X0Cb, Ya0, Ya1, Yb0, Yb1;

  // ---- prologue: fill pipe with pair p; prep pair p+W ----
  tCa = tix[p * 32 + m];      rCa = rho[p * 32 + m];
  tCb = tix[p * 32 + 16 + m]; rCb = rho[p * 32 + 16 + m];
  {
    const int p1 = min(p + W, plim);
    tNa = tix[p1 * 32 + m];      rNa = rho[p1 * 32 + m];
    tNb = tix[p1 * 32 + 16 + m]; rNb = rho[p1 * 32 + 16 + m];
  }
  X0Ca.v8 = *(const half8*)(embh + (size_t)min(max(tCa - 1, 0), 510) * 32 + q * 8);
  X0Cb.v8 = *(const half8*)(embh + (size_t)min(max(tCb - 1, 0), 510) * 32 + q * 8);
  phase1(rCa, X0Ca.v8, Ya0, Ya1);
  phase1(rCb, X0Cb.v8, Yb0, Yb1);
  icPa = tCa; icPb = tCb; pP = p;
  X0Ca.v8 = *(const half8*)(embh + (size_t)min(max(tNa - 1, 0), 510) * 32 + q * 8);
  X0Cb.v8 = *(const half8*)(embh + (size_t)min(max(tNb - 1, 0), 510) * 32 + q * 8);
  tCa = tNa; rCa = rNa; tCb = tNb; rCb = rNb;
  {
    const int p2 = min(p + 2 * W, plim);
    tNa = tix[p2 * 32 + m];      rNa = rho[p2 * 32 + m];
    tNb = tix[p2 * 32 + 16 + m]; rNb = rho[p2 * 32 + 16 + m];
  }
  p += W;

  // ---- steady state: 2x phase2(pair k-1) ; 2x phase1(pair k) ----
  while (p < npairs) {
    // prefetch: tix/rho 2 pairs ahead; emb 1 pair ahead (tN >=1 iter old)
    const int pf = min(p + 2 * W, plim);
    const int   tQa = tix[pf * 32 + m],      tQb = tix[pf * 32 + 16 + m];
    const float rQa = rho[pf * 32 + m],      rQb = rho[pf * 32 + 16 + m];
    const half8 X0Na = *(const half8*)(embh + (size_t)min(max(tNa - 1, 0), 510) * 32 + q * 8);
    const half8 X0Nb = *(const half8*)(embh + (size_t)min(max(tNb - 1, 0), 510) * 32 + q * 8);

    // finish pair k-1: two independent L1 chains, one merged 128B store
    const float tha = phase2core(Ya0, Ya1);
    const float thb = phase2core(Yb0, Yb1);
    {
      const float vala = (icPa == 0) ? IC_VAL : tha * CSANMAX;
      const float valb = (icPb == 0) ? IC_VAL : thb * CSANMAX;
      const float v = (q & 1) ? valb : vala;
      if (q < 2) out[pP * 32 + q * 16 + m] = v;
    }
    // start pair k: two independent L0 chains
    phase1(rCa, X0Ca.v8, Ya0, Ya1);
    phase1(rCb, X0Cb.v8, Yb0, Yb1);

    icPa = tCa; icPb = tCb; pP = p;
    X0Ca.v8 = X0Na; X0Cb.v8 = X0Nb;    // fragments carried, no repack
    tCa = tNa; rCa = rNa; tCb = tNb; rCb = rNb;
    tNa = tQa; rNa = rQa; tNb = tQb; rNb = rQb;
    p += W;
  }

  // ---- epilogue: drain the last pair ----
  {
    const float tha = phase2core(Ya0, Ya1);
    const float thb = phase2core(Yb0, Yb1);
    const float vala = (icPa == 0) ? IC_VAL : tha * CSANMAX;
    const float valb = (icPb == 0) ? IC_VAL : thb * CSANMAX;
    const float v = (q & 1) ? valb : vala;
    if (q < 2) out[pP * 32 + q * 16 + m] = v;
  }
}

extern "C" void kernel_launch(void* const* d_in, const int* in_sizes, int n_in,
                              void* d_out, int out_size, void* d_ws, size_t ws_size,
                              hipStream_t stream) {
  const int*   tix  = (const int*)d_in[0];
  const float* rho  = (const float*)d_in[1];
  const float* emb  = (const float*)d_in[2];
  const float* W0   = (const float*)d_in[3];
  const float* b0   = (const float*)d_in[4];
  const float* W1   = (const float*)d_in[5];
  const float* b1   = (const float*)d_in[6];
  const float* Wout = (const float*)d_in[7];
  const float* bout = (const float*)d_in[8];
  float* outp = (float*)d_out;

  const int n      = in_sizes[0];    // 2,000,000 (divisible by 32)
  const int npairs = n / 32;         // 62,500 pairs of 16-pt tiles

  // ---- one-time emb f32->f16 into workspace (32704 B) ----
  _Float16* embh = (_Float16*)d_ws;
  const int nelem2 = (511 * 32) / 2;               // f16 pairs
  emb_cvt<<<dim3((nelem2 + 255) / 256), dim3(256), 0, stream>>>(emb, embh, nelem2);

  // 4-wave blocks, 16384 B LDS. Grid 512 = exactly 2 blocks/CU; each wave
  // runs ~30.5 pair-iterations (61 tiles).
  int grid = 512;
  const int maxg = (npairs + 3) / 4;
  if (grid > maxg) grid = maxg;
  mlp_kernel<<<dim3(grid), dim3(256), 0, stream>>>(
      tix, rho, embh, W0, b0, W1, b1, Wout, bout, outp, npairs);
}

// Round 21
// 154.181 us; speedup vs baseline: 1.0394x; 1.0166x over previous
//
#include <hip/hip_runtime.h>
#include <stdint.h>

// Fused MLP decode, MFMA f16. ROUND 21: QUAD (4-tile) pipeline on the lean
// base. Pair-widening (R20) paid +3.4% with zero spill at 144 unified regs
// -- same lever, one more notch. State over R20: +2x(X0 4 + Y 8 + ~5
// scalars) ~= +35 arch -> ~180-205 unified, above lb(256,3)'s ~170 cap ->
// lb(256,2) raises the cap to 256 (occupancy pinned at 2 waves/SIMD all
// session regardless -- R3/R8/R11 -- so nothing lost).
// Pressure control: explicit a/b/c/d scalars (rule-#20 safe, no dynamic
// indexing) and stores split into two 128B halves so {a,b} acc state dies
// before {c,d} phase2 runs.
// PRE-COMMITTED: WRITE_SIZE must stay 7812.5 (jump = spill = revert to
// R20 as final). Expect kernel 84-87us if quad-ILP pays; >=88 = lever
// exhausted.
// Kept (validated): zero-LDS loop + interleave (R12), weights AGPR-
// resident (R4/R8), hmap-permuted W1 (R11), b1 as true MFMA C (R18),
// staged-Wout dot-MFMA epilogue (R16), usilu1 (R15), split Chebyshev
// (R17), grid 512 = 2 blocks/CU (R17), f16 emb table in d_ws (R19),
// tix/rho 2-ahead + emb 1-ahead prefetch (R13 lesson).
// Loop: zero DS ops, zero barriers. n % 64 == 0 (2,000,000 = 64*31,250).

typedef _Float16 half8  __attribute__((ext_vector_type(8)));
typedef _Float16 half4v __attribute__((ext_vector_type(4)));
typedef _Float16 half2v __attribute__((ext_vector_type(2)));
typedef float f32x4 __attribute__((ext_vector_type(4)));

#define LOG2E 1.44269504088896340736f
#define NLN2  -0.6931471805599453f         // -ln2 = 1/(-log2e)
#define CSCL  -1.44269504088896340736f     // c = -log2e
#define BASE_LOGIT -0.84729786038720367f   // log(0.3/0.7)
#define CSANMAX 28700.0f
#define IC_VAL 8610.0f                     // 0.3 * 28700

__device__ __forceinline__ float fast_exp2(float x) { return __builtin_amdgcn_exp2f(x); }
__device__ __forceinline__ float fast_rcp(float x)  { return __builtin_amdgcn_rcpf(x); }
// direct u-domain silu: input u (= c*x), output p = u*sigma = c*silu(x).
__device__ __forceinline__ float usilu1(float u) {
  return u * fast_rcp(1.0f + fast_exp2(u));
}
__device__ __forceinline__ half2v pkh(float a, float b) {
  return __builtin_bit_cast(half2v, __builtin_amdgcn_cvt_pkrtz(a, b));
}

union H8 { half8 v8; half2v v2[4]; half4v v4[2]; };
union H4 { half4v v4; half2v v2[2]; };

// ---- pre-kernel: emb (511x32 f32) -> f16 once, cvt_pkrtz rounding ----
__global__ __launch_bounds__(256) void emb_cvt(
    const float* __restrict__ emb, _Float16* __restrict__ embh, int nelem2)
{
  const int i = blockIdx.x * 256 + threadIdx.x;   // one f16 PAIR per thread
  if (i < nelem2) {
    const float a = emb[i * 2];
    const float b = emb[i * 2 + 1];
    *(half2v*)&embh[i * 2] = pkh(a, b);           // same rounding as R18
  }
}

__global__ __launch_bounds__(256, 2) void mlp_kernel(
    const int* __restrict__ tix, const float* __restrict__ rho,
    const _Float16* __restrict__ embh, const float* __restrict__ W0,
    const float* __restrict__ b0, const float* __restrict__ W1,
    const float* __restrict__ b1, const float* __restrict__ Wout,
    const float* __restrict__ bout, float* __restrict__ out, int nquads)
{
  // Weight staging ONLY (init, 16384 B). No H buffer.
  __shared__ __align__(16) _Float16 stage[2][2][4][64][8];

  const int tid  = threadIdx.x;
  const int wid  = tid >> 6;
  const int lane = tid & 63;
  const int m    = lane & 15;
  const int q    = lane >> 4;

  // ---- init: wave 0 builds the swizzled weight fragments ----
  // W0 (A-op, => W0^T): k=s*32+q*8+j, n=t*16+m; feature rows PERMUTED
  // (k-window 32..63 = [cos1..8|sin1..8|rho,b0(1.0),0pad]); pre-scaled by c.
  // W1 (A-op, => W1^T): rows hmap-permuted so L1's B-operand is L0's
  // register output directly: hmap(k) = (s*2+(j>>2))*16 + q*4 + (j&3).
  if (wid == 0) {
#pragma unroll
    for (int t = 0; t < 4; ++t) {
#pragma unroll
      for (int s = 0; s < 2; ++s) {
        half8 f0, f1;
#pragma unroll
        for (int j = 0; j < 8; ++j) {
          const int k = s * 32 + q * 8 + j;
          const int n = t * 16 + m;
          float v0;
          if (k < 32) {
            v0 = W0[k * 64 + n];
          } else {
            const int kn = k - 32;
            v0 = (kn < 16) ? W0[(33 + kn) * 64 + n]
               : (kn == 16) ? W0[32 * 64 + n]
               : (kn == 17) ? b0[n] : 0.0f;
          }
          f0[j] = (_Float16)(CSCL * v0);
          const int hm = (s * 2 + (j >> 2)) * 16 + q * 4 + (j & 3);
          f1[j] = (_Float16)W1[hm * 64 + n];   // W1 UNSCALED, hmap-permuted
        }
        *(half8*)&stage[0][s][t][lane][0] = f0;
        *(half8*)&stage[1][s][t][lane][0] = f1;
      }
    }
  }

  // ---- persistent epilogue constants ----
  // b1 as TRUE L1 C-operand (u-domain): lane (q,m) owns h = t*16 + q*4 + r.
  f32x4 bq1acc[4];
#pragma unroll
  for (int t = 0; t < 4; ++t) {
    const f32x4 bv = *(const f32x4*)(b1 + t * 16 + q * 4);
#pragma unroll
    for (int r = 0; r < 4; ++r) bq1acc[t][r] = CSCL * bv[r];
  }
  // Wout as dot-MFMA A-fragments (rows identical; -ln2-scaled):
  // A[row=*][k=q*8+j] = NLN2 * Wout[h'], h' = (j>>2)*16+q*4+(j&3) (+32 B-half).
  H8 wdA, wdB;
#pragma unroll
  for (int a = 0; a < 4; ++a) {
    const int j0 = 2 * a, j1 = 2 * a + 1;
    const int h0 = ((j0 >> 2) * 16) + q * 4 + (j0 & 3);
    const int h1 = ((j1 >> 2) * 16) + q * 4 + (j1 & 3);
    wdA.v2[a] = pkh(NLN2 * Wout[h0],      NLN2 * Wout[h1]);
    wdB.v2[a] = pkh(NLN2 * Wout[32 + h0], NLN2 * Wout[32 + h1]);
  }
  const float boutBL = bout[0] + BASE_LOGIT;
  const f32x4 cBL = {boutBL, boutBL, boutBL, boutBL};   // dot-MFMA C-operand

  __syncthreads();   // staged weights visible

  // ---- hoist ALL weight fragments to registers (loop-invariant) ----
  half8 w0A[4], w0B[4], w1A[4], w1B[4];
#pragma unroll
  for (int t = 0; t < 4; ++t) {
    w0A[t] = *(const half8*)&stage[0][0][t][lane][0];
    w0B[t] = *(const half8*)&stage[0][1][t][lane][0];
    w1A[t] = *(const half8*)&stage[1][0][t][lane][0];
    w1B[t] = *(const half8*)&stage[1][1][t][lane][0];
  }

  const f32x4 z = {0.0f, 0.0f, 0.0f, 0.0f};
  const int W = gridDim.x * 4;

  int p = blockIdx.x * 4 + wid;      // quad index: tiles 4p..4p+3
  if (p >= nquads) return;           // after the barrier: safe
  const int plim = nquads - 1;

  // ---- phase1: feat -> L0 -> silu -> packed Y (registers only) ----
  auto phase1 = [&](float rhp, half8 X0v, H8& Y0o, H8& Y1o) {
    const float rev = 0.5f * rhp;  // v_sin/v_cos take revolutions
    const float c1  = __builtin_amdgcn_cosf(rev);
    const float s1f = __builtin_amdgcn_sinf(rev);
    const float tc  = 2.0f * c1;
    const float x1v = (q == 0) ? c1 : ((q == 1) ? s1f : 0.0f);
    const float x0v = (q == 0) ? 1.0f : 0.0f;
    // even/odd split: x_{k+2} = uu*x_k - x_{k-2}, uu = 2cos(2a) = tc^2-2.
    const float x2v = tc * x1v - x0v;
    const float x3v = tc * x2v - x1v;
    const float uu  = tc * tc - 2.0f;
    const float x4v = uu * x2v - x0v;
    const float x5v = uu * x3v - x1v;
    const float x6v = uu * x4v - x2v;
    const float x7v = uu * x5v - x3v;
    const float x8v = uu * x6v - x4v;
    H8 X1;
    X1.v2[0] = (q == 2) ? pkh(rhp, 1.0f) : pkh(x1v, x2v);  // q==2: (rho, b0-slot)
    X1.v2[1] = pkh(x3v, x4v);
    X1.v2[2] = pkh(x5v, x6v);
    X1.v2[3] = pkh(x7v, x8v);

    f32x4 acc[4];
#pragma unroll
    for (int t = 0; t < 4; ++t) {
      f32x4 a = __builtin_amdgcn_mfma_f32_16x16x32_f16(w0A[t], X0v, z, 0, 0, 0);
      a = __builtin_amdgcn_mfma_f32_16x16x32_f16(w0B[t], X1.v8, a, 0, 0, 0);
      acc[t] = a;
    }
    H4 hh[4];
#pragma unroll
    for (int t = 0; t < 4; ++t) {
      hh[t].v2[0] = pkh(usilu1(acc[t][0]), usilu1(acc[t][1]));
      hh[t].v2[1] = pkh(usilu1(acc[t][2]), usilu1(acc[t][3]));
    }
    Y0o.v4[0] = hh[0].v4; Y0o.v4[1] = hh[1].v4;   // hmap makes this exact
    Y1o.v4[0] = hh[2].v4; Y1o.v4[1] = hh[3].v4;
  };

  // ---- phase2core: L1(carried Y, C=c*b1) -> silu -> dot-MFMA -> theta ----
  auto phase2core = [&](const H8& Y0p, const H8& Y1p) -> float {
    f32x4 acc[4];
#pragma unroll
    for (int t = 0; t < 4; ++t) {
      f32x4 a = __builtin_amdgcn_mfma_f32_16x16x32_f16(w1A[t], Y0p.v8, bq1acc[t], 0, 0, 0);
      a = __builtin_amdgcn_mfma_f32_16x16x32_f16(w1B[t], Y1p.v8, a, 0, 0, 0);
      acc[t] = a;   // u = W1^T p + c*b1 (bias folded into MFMA C)
    }
    H4 hh2[4];
#pragma unroll
    for (int t = 0; t < 4; ++t) {
      hh2[t].v2[0] = pkh(usilu1(acc[t][0]), usilu1(acc[t][1]));
      hh2[t].v2[1] = pkh(usilu1(acc[t][2]), usilu1(acc[t][3]));
    }
    H8 B0, B1;
    B0.v4[0] = hh2[0].v4; B0.v4[1] = hh2[1].v4;   // B[k][col=m], h'(k) staged
    B1.v4[0] = hh2[2].v4; B1.v4[1] = hh2[3].v4;
    f32x4 d2 = __builtin_amdgcn_mfma_f32_16x16x32_f16(wdA.v8, B0.v8, cBL, 0, 0, 0);
    d2 = __builtin_amdgcn_mfma_f32_16x16x32_f16(wdB.v8, B1.v8, d2, 0, 0, 0);
    // all A rows equal -> every lane's d2[0] = dot(point m) + boutBL
    return fast_rcp(1.0f + fast_exp2(-LOG2E * d2[0]));
  };

  // ---- pipeline state (explicit scalars: rule-#20 safe) ----
  int   tCa, tCb, tCc, tCd, tNa, tNb, tNc, tNd;
  int   icPa, icPb, icPc, icPd, pP;
  float rCa, rCb, rCc, rCd, rNa, rNb, rNc, rNd;
  H8 X0Ca, X0Cb, X0Cc, X0Cd;
  H8 Ya0, Ya1, Yb0, Yb1, Yc0, Yc1, Yd0, Yd1;

  // ---- prologue: fill pipe with quad p; prep quad p+W ----
  tCa = tix[p * 64 + m];      rCa = rho[p * 64 + m];
  tCb = tix[p * 64 + 16 + m]; rCb = rho[p * 64 + 16 + m];
  tCc = tix[p * 64 + 32 + m]; rCc = rho[p * 64 + 32 + m];
  tCd = tix[p * 64 + 48 + m]; rCd = rho[p * 64 + 48 + m];
  {
    const int p1 = min(p + W, plim);
    tNa = tix[p1 * 64 + m];      rNa = rho[p1 * 64 + m];
    tNb = tix[p1 * 64 + 16 + m]; rNb = rho[p1 * 64 + 16 + m];
    tNc = tix[p1 * 64 + 32 + m]; rNc = rho[p1 * 64 + 32 + m];
    tNd = tix[p1 * 64 + 48 + m]; rNd = rho[p1 * 64 + 48 + m];
  }
  X0Ca.v8 = *(const half8*)(embh + (size_t)min(max(tCa - 1, 0), 510) * 32 + q * 8);
  X0Cb.v8 = *(const half8*)(embh + (size_t)min(max(tCb - 1, 0), 510) * 32 + q * 8);
  X0Cc.v8 = *(const half8*)(embh + (size_t)min(max(tCc - 1, 0), 510) * 32 + q * 8);
  X0Cd.v8 = *(const half8*)(embh + (size_t)min(max(tCd - 1, 0), 510) * 32 + q * 8);
  phase1(rCa, X0Ca.v8, Ya0, Ya1);
  phase1(rCb, X0Cb.v8, Yb0, Yb1);
  phase1(rCc, X0Cc.v8, Yc0, Yc1);
  phase1(rCd, X0Cd.v8, Yd0, Yd1);
  icPa = tCa; icPb = tCb; icPc = tCc; icPd = tCd; pP = p;
  X0Ca.v8 = *(const half8*)(embh + (size_t)min(max(tNa - 1, 0), 510) * 32 + q * 8);
  X0Cb.v8 = *(const half8*)(embh + (size_t)min(max(tNb - 1, 0), 510) * 32 + q * 8);
  X0Cc.v8 = *(const half8*)(embh + (size_t)min(max(tNc - 1, 0), 510) * 32 + q * 8);
  X0Cd.v8 = *(const half8*)(embh + (size_t)min(max(tNd - 1, 0), 510) * 32 + q * 8);
  tCa = tNa; rCa = rNa; tCb = tNb; rCb = rNb;
  tCc = tNc; rCc = rNc; tCd = tNd; rCd = rNd;
  {
    const int p2 = min(p + 2 * W, plim);
    tNa = tix[p2 * 64 + m];      rNa = rho[p2 * 64 + m];
    tNb = tix[p2 * 64 + 16 + m]; rNb = rho[p2 * 64 + 16 + m];
    tNc = tix[p2 * 64 + 32 + m]; rNc = rho[p2 * 64 + 32 + m];
    tNd = tix[p2 * 64 + 48 + m]; rNd = rho[p2 * 64 + 48 + m];
  }
  p += W;

  // ---- steady state: 4x phase2(quad k-1) ; 4x phase1(quad k) ----
  while (p < nquads) {
    // prefetch: tix/rho 2 quads ahead; emb 1 quad ahead (tN >=1 iter old)
    const int pf = min(p + 2 * W, plim);
    const int   tQa = tix[pf * 64 + m],      tQb = tix[pf * 64 + 16 + m];
    const int   tQc = tix[pf * 64 + 32 + m], tQd = tix[pf * 64 + 48 + m];
    const float rQa = rho[pf * 64 + m],      rQb = rho[pf * 64 + 16 + m];
    const float rQc = rho[pf * 64 + 32 + m], rQd = rho[pf * 64 + 48 + m];
    const half8 X0Na = *(const half8*)(embh + (size_t)min(max(tNa - 1, 0), 510) * 32 + q * 8);
    const half8 X0Nb = *(const half8*)(embh + (size_t)min(max(tNb - 1, 0), 510) * 32 + q * 8);
    const half8 X0Nc = *(const half8*)(embh + (size_t)min(max(tNc - 1, 0), 510) * 32 + q * 8);
    const half8 X0Nd = *(const half8*)(embh + (size_t)min(max(tNd - 1, 0), 510) * 32 + q * 8);

    // finish quad k-1: {a,b} then 128B store (acc state dies), {c,d} + store
    {
      const float tha = phase2core(Ya0, Ya1);
      const float thb = phase2core(Yb0, Yb1);
      const float vala = (icPa == 0) ? IC_VAL : tha * CSANMAX;
      const float valb = (icPb == 0) ? IC_VAL : thb * CSANMAX;
      if (q < 2) out[pP * 64 + q * 16 + m] = (q & 1) ? valb : vala;
    }
    {
      const float thc = phase2core(Yc0, Yc1);
      const float thd = phase2core(Yd0, Yd1);
      const float valc = (icPc == 0) ? IC_VAL : thc * CSANMAX;
      const float vald = (icPd == 0) ? IC_VAL : thd * CSANMAX;
      if (q < 2) out[pP * 64 + 32 + q * 16 + m] = (q & 1) ? vald : valc;
    }
    // start quad k: four independent L0 chains
    phase1(rCa, X0Ca.v8, Ya0, Ya1);
    phase1(rCb, X0Cb.v8, Yb0, Yb1);
    phase1(rCc, X0Cc.v8, Yc0, Yc1);
    phase1(rCd, X0Cd.v8, Yd0, Yd1);

    icPa = tCa; icPb = tCb; icPc = tCc; icPd = tCd; pP = p;
    X0Ca.v8 = X0Na; X0Cb.v8 = X0Nb; X0Cc.v8 = X0Nc; X0Cd.v8 = X0Nd;
    tCa = tNa; rCa = rNa; tCb = tNb; rCb = rNb;
    tCc = tNc; rCc = rNc; tCd = tNd; rCd = rNd;
    tNa = tQa; rNa = rQa; tNb = tQb; rNb = rQb;
    tNc = tQc; rNc = rQc; tNd = tQd; rNd = rQd;
    p += W;
  }

  // ---- epilogue: drain the last quad ----
  {
    const float tha = phase2core(Ya0, Ya1);
    const float thb = phase2core(Yb0, Yb1);
    const float vala = (icPa == 0) ? IC_VAL : tha * CSANMAX;
    const float valb = (icPb == 0) ? IC_VAL : thb * CSANMAX;
    if (q < 2) out[pP * 64 + q * 16 + m] = (q & 1) ? valb : vala;
    const float thc = phase2core(Yc0, Yc1);
    const float thd = phase2core(Yd0, Yd1);
    const float valc = (icPc == 0) ? IC_VAL : thc * CSANMAX;
    const float vald = (icPd == 0) ? IC_VAL : thd * CSANMAX;
    if (q < 2) out[pP * 64 + 32 + q * 16 + m] = (q & 1) ? vald : valc;
  }
}

extern "C" void kernel_launch(void* const* d_in, const int* in_sizes, int n_in,
                              void* d_out, int out_size, void* d_ws, size_t ws_size,
                              hipStream_t stream) {
  const int*   tix  = (const int*)d_in[0];
  const float* rho  = (const float*)d_in[1];
  const float* emb  = (const float*)d_in[2];
  const float* W0   = (const float*)d_in[3];
  const float* b0   = (const float*)d_in[4];
  const float* W1   = (const float*)d_in[5];
  const float* b1   = (const float*)d_in[6];
  const float* Wout = (const float*)d_in[7];
  const float* bout = (const float*)d_in[8];
  float* outp = (float*)d_out;

  const int n      = in_sizes[0];    // 2,000,000 (divisible by 64)
  const int nquads = n / 64;         // 31,250 quads of 16-pt tiles

  // ---- one-time emb f32->f16 into workspace (32704 B) ----
  _Float16* embh = (_Float16*)d_ws;
  const int nelem2 = (511 * 32) / 2;               // f16 pairs
  emb_cvt<<<dim3((nelem2 + 255) / 256), dim3(256), 0, stream>>>(emb, embh, nelem2);

  // 4-wave blocks, 16384 B LDS. Grid 512 = 2 blocks/CU; each wave runs
  // ~15.3 quad-iterations (61 tiles).
  int grid = 512;
  const int maxg = (nquads + 3) / 4;
  if (grid > maxg) grid = maxg;
  mlp_kernel<<<dim3(grid), dim3(256), 0, stream>>>(
      tix, rho, embh, W0, b0, W1, b1, Wout, bout, outp, nquads);
}